// Round 3
// baseline (168.005 us; speedup 1.0000x reference)
//
#include <hip/hip_runtime.h>

constexpr int S    = 256;
constexpr int NL   = 17;
constexpr int L    = 19;   // start = 17, end = 18
constexpr int CAPB = 16384;

typedef float v4 __attribute__((ext_vector_type(4), aligned(4)));

// per-sequence scratch: fwd state Z, bwd state V (pre el_mid), log-scale factors
__device__ float g_Z[CAPB * 17];
__device__ float g_V[CAPB * 17];
__device__ float g_mf[CAPB];
__device__ float g_mv[CAPB];

// ---------------------------------------------------------------------------
// BIOES sparsity (labels: 0=O; per type t in {PER,ORG,LOC,MISC}: B=1+4t,
// I=2+4t, E=3+4t, S=4+4t). allowed(to=i, from=j):
//   j in {O,E*,S*} -> i in {O,B*,S*}   (9x9 = 81 dense block)
//   j in {B_t,I_t} -> i in {I_t,E_t}   (16 pair terms)
// Fwd rows (to i, cols j): wide rows {0,1,4,5,8,9,12,13,16} over cols
// {0,3,4,7,8,11,12,15,16}; pairs (i,j): (2,1)(2,2)(3,1)(3,2) per type.
// Bwd is the transpose support with cf[i][j] = exp(T[j*19+i]).
// ---------------------------------------------------------------------------
#define ROWF(X,i) X(i,0) X(i,3) X(i,4) X(i,7) X(i,8) X(i,11) X(i,12) X(i,15) X(i,16)
#define FWD_ALL(X) \
  ROWF(X,0) ROWF(X,1) ROWF(X,4) ROWF(X,5) ROWF(X,8) ROWF(X,9) ROWF(X,12) ROWF(X,13) ROWF(X,16) \
  X(2,1) X(2,2) X(3,1) X(3,2) X(6,5) X(6,6) X(7,5) X(7,6) \
  X(10,9) X(10,10) X(11,9) X(11,10) X(14,13) X(14,14) X(15,13) X(15,14)

#define ROWB(X,i) X(i,0) X(i,1) X(i,4) X(i,5) X(i,8) X(i,9) X(i,12) X(i,13) X(i,16)
#define BWD_ALL(X) \
  ROWB(X,0) ROWB(X,3) ROWB(X,4) ROWB(X,7) ROWB(X,8) ROWB(X,11) ROWB(X,12) ROWB(X,15) ROWB(X,16) \
  X(1,2) X(1,3) X(2,2) X(2,3) X(5,6) X(5,7) X(6,6) X(6,7) \
  X(9,10) X(9,11) X(10,10) X(10,11) X(13,14) X(13,15) X(14,14) X(14,15)

#define APPLY17(X) X(0) X(1) X(2) X(3) X(4) X(5) X(6) X(7) X(8) X(9) X(10) X(11) X(12) X(13) X(14) X(15) X(16)

// coefficient declarations (all wave-uniform values, but live in VGPRs)
#define DCF_F(i,j) const float cf_##i##_##j = __expf(Tg[(i)*19+(j)]);
#define DCF_B(i,j) const float cf_##i##_##j = __expf(Tg[(j)*19+(i)]);

// state vector p0..p16
#define DPF(i) float p##i = __expf(Tg[(i)*19+17]);   // E[i, start]
#define DPB(i) float p##i = __expf(Tg[18*19+(i)]);   // E[end, i]

// token slot: 17 named floats
#define DECLSLOT(T) float T##0,T##1,T##2,T##3,T##4,T##5,T##6,T##7,T##8,T##9, \
                          T##10,T##11,T##12,T##13,T##14,T##15,T##16;

#define LOADTOK(T, OFF) { \
    const char* a_ = base + (OFF); \
    const v4 x0_ = *(const v4*)(a_); \
    const v4 x1_ = *(const v4*)(a_ + 16); \
    const v4 x2_ = *(const v4*)(a_ + 32); \
    const v4 x3_ = *(const v4*)(a_ + 48); \
    const float x4_ = *(const float*)(a_ + 64); \
    T##0=x0_.x; T##1=x0_.y; T##2=x0_.z; T##3=x0_.w; \
    T##4=x1_.x; T##5=x1_.y; T##6=x1_.z; T##7=x1_.w; \
    T##8=x2_.x; T##9=x2_.y; T##10=x2_.z; T##11=x2_.w; \
    T##12=x3_.x; T##13=x3_.y; T##14=x3_.z; T##15=x3_.w; T##16=x4_; }

// q_j = exp(logit_j) * p_j, all 17
#define MKQALL(T) \
    const float q0 = __expf(T##0) * p0;   const float q1 = __expf(T##1) * p1; \
    const float q2 = __expf(T##2) * p2;   const float q3 = __expf(T##3) * p3; \
    const float q4 = __expf(T##4) * p4;   const float q5 = __expf(T##5) * p5; \
    const float q6 = __expf(T##6) * p6;   const float q7 = __expf(T##7) * p7; \
    const float q8 = __expf(T##8) * p8;   const float q9 = __expf(T##9) * p9; \
    const float q10 = __expf(T##10) * p10; const float q11 = __expf(T##11) * p11; \
    const float q12 = __expf(T##12) * p12; const float q13 = __expf(T##13) * p13; \
    const float q14 = __expf(T##14) * p14; const float q15 = __expf(T##15) * p15; \
    const float q16 = __expf(T##16) * p16;

#define FMQ(i,j) cf_##i##_##j * q##j
#define ROW9N(i,a,b,c,d,e,f,g,h,k) \
    const float n##i = (((FMQ(i,a)+FMQ(i,b)) + (FMQ(i,c)+FMQ(i,d))) + \
                        ((FMQ(i,e)+FMQ(i,f)) + (FMQ(i,g)+FMQ(i,h)))) + FMQ(i,k);
#define ROW2N(i,a,b) const float n##i = FMQ(i,a) + FMQ(i,b);

#define MATVEC_F \
    ROW9N(0,0,3,4,7,8,11,12,15,16)  ROW9N(1,0,3,4,7,8,11,12,15,16) \
    ROW9N(4,0,3,4,7,8,11,12,15,16)  ROW9N(5,0,3,4,7,8,11,12,15,16) \
    ROW9N(8,0,3,4,7,8,11,12,15,16)  ROW9N(9,0,3,4,7,8,11,12,15,16) \
    ROW9N(12,0,3,4,7,8,11,12,15,16) ROW9N(13,0,3,4,7,8,11,12,15,16) \
    ROW9N(16,0,3,4,7,8,11,12,15,16) \
    ROW2N(2,1,2)   ROW2N(3,1,2)   ROW2N(6,5,6)   ROW2N(7,5,6) \
    ROW2N(10,9,10) ROW2N(11,9,10) ROW2N(14,13,14) ROW2N(15,13,14)

#define MATVEC_B \
    ROW9N(0,0,1,4,5,8,9,12,13,16)  ROW9N(3,0,1,4,5,8,9,12,13,16) \
    ROW9N(4,0,1,4,5,8,9,12,13,16)  ROW9N(7,0,1,4,5,8,9,12,13,16) \
    ROW9N(8,0,1,4,5,8,9,12,13,16)  ROW9N(11,0,1,4,5,8,9,12,13,16) \
    ROW9N(12,0,1,4,5,8,9,12,13,16) ROW9N(15,0,1,4,5,8,9,12,13,16) \
    ROW9N(16,0,1,4,5,8,9,12,13,16) \
    ROW2N(1,2,3)   ROW2N(2,2,3)   ROW2N(5,6,7)   ROW2N(6,6,7) \
    ROW2N(9,10,11) ROW2N(10,10,11) ROW2N(13,14,15) ROW2N(14,14,15)

#define ASG(i)  p##i = n##i;
#define ASGR(i) p##i = n##i * r_;

#define STORE_P { \
    float* d_ = SC + bc * 17; \
    d_[0]=p0; d_[1]=p1; d_[2]=p2; d_[3]=p3; d_[4]=p4; d_[5]=p5; d_[6]=p6; d_[7]=p7; \
    d_[8]=p8; d_[9]=p9; d_[10]=p10; d_[11]=p11; d_[12]=p12; d_[13]=p13; d_[14]=p14; \
    d_[15]=p15; d_[16]=p16; \
    SM[bc] = m; }

// One recurrence step: consume slot T (token T_), prefetch token T_+4 into T.
// Lanes past their nup keep computing bounded garbage; their state was already
// stored at the trigger step, so no per-step select/freeze is needed.
#define CHAINSTEP(T, T_, OFFV, RN, MV, DOCLAMP, SSTR) { \
    MKQALL(T) \
    OFFV += (SSTR); \
    if (DOCLAMP) { if (OFFV < capLo) OFFV = capLo; } \
    LOADTOK(T, OFFV) \
    MV \
    if (RN) { \
        float mxA = fmaxf(fmaxf(n0,n1),  fmaxf(n2,n3)); \
        float mxB = fmaxf(fmaxf(n4,n5),  fmaxf(n6,n7)); \
        float mxC = fmaxf(fmaxf(n8,n9),  fmaxf(n10,n11)); \
        float mxD = fmaxf(fmaxf(n12,n13),fmaxf(n14,n15)); \
        float mx  = fmaxf(fmaxf(fmaxf(mxA,mxB), fmaxf(mxC,mxD)), n16); \
        const float r_ = __frcp_rn(mx); \
        m += __logf(mx); \
        APPLY17(ASGR) \
    } else { \
        APPLY17(ASG) \
    } \
    if ((T_) == nup - 1) STORE_P \
}

__device__ __forceinline__ void chainF(const float* __restrict__ logits,
                                       const int* __restrict__ lens,
                                       const float* __restrict__ Tg, int B, int z)
{
    const int  lane  = threadIdx.x;
    const int  braw  = z * 64 + lane;
    const bool valid = braw < B;
    const int  bc    = valid ? braw : 0;
    const int  len   = lens[bc];
    const int  mid   = len >> 1;
    const int  nup   = valid ? mid : 0;

    FWD_ALL(DCF_F)
    APPLY17(DPF)
    float  m  = 0.0f;
    float* SC = g_Z;
    float* SM = g_mf;
    if (nup == 0 && valid) STORE_P

    int nmax = nup;
    #pragma unroll
    for (int o = 32; o >= 1; o >>= 1) nmax = max(nmax, __shfl_xor(nmax, o));
    nmax = (nmax + 3) & ~3;

    const char* base  = (const char*)logits;
    const int   sb4   = bc * (S * NL * 4);
    const int   capLo = sb4;                   // unused in fwd (DOCLAMP=0)
    int off0 = sb4, off1 = sb4 + 68, off2 = sb4 + 136, off3 = sb4 + 204;

    DECLSLOT(sA) DECLSLOT(sB) DECLSLOT(sC) DECLSLOT(sD)
    LOADTOK(sA, off0) LOADTOK(sB, off1) LOADTOK(sC, off2) LOADTOK(sD, off3)

    for (int tb = 0; tb < nmax; tb += 4) {
        CHAINSTEP(sA, tb,     off0, 0, MATVEC_F, 0, 272)
        CHAINSTEP(sB, tb + 1, off1, 0, MATVEC_F, 0, 272)
        CHAINSTEP(sC, tb + 2, off2, 0, MATVEC_F, 0, 272)
        CHAINSTEP(sD, tb + 3, off3, 1, MATVEC_F, 0, 272)
    }
}

__device__ __forceinline__ void chainB(const float* __restrict__ logits,
                                       const int* __restrict__ lens,
                                       const float* __restrict__ Tg, int B, int z)
{
    const int  lane  = threadIdx.x;
    const int  braw  = z * 64 + lane;
    const bool valid = braw < B;
    const int  bc    = valid ? braw : 0;
    const int  len   = lens[bc];
    const int  mid   = len >> 1;
    const int  nup   = valid ? (len - 1 - mid) : 0;

    BWD_ALL(DCF_B)
    APPLY17(DPB)
    float  m  = 0.0f;
    float* SC = g_V;
    float* SM = g_mv;
    if (nup == 0 && valid) STORE_P

    int nmax = nup;
    #pragma unroll
    for (int o = 32; o >= 1; o >>= 1) nmax = max(nmax, __shfl_xor(nmax, o));
    nmax = (nmax + 3) & ~3;

    const char* base  = (const char*)logits;
    const int   sb4   = bc * (S * NL * 4);
    const int   capLo = sb4;
    const int   t0    = len - 1;
    int off0 = sb4 + max(t0,     0) * 68;
    int off1 = sb4 + max(t0 - 1, 0) * 68;
    int off2 = sb4 + max(t0 - 2, 0) * 68;
    int off3 = sb4 + max(t0 - 3, 0) * 68;

    DECLSLOT(sA) DECLSLOT(sB) DECLSLOT(sC) DECLSLOT(sD)
    LOADTOK(sA, off0) LOADTOK(sB, off1) LOADTOK(sC, off2) LOADTOK(sD, off3)

    for (int tb = 0; tb < nmax; tb += 4) {
        CHAINSTEP(sA, tb,     off0, 0, MATVEC_B, 1, -272)
        CHAINSTEP(sB, tb + 1, off1, 0, MATVEC_B, 1, -272)
        CHAINSTEP(sC, tb + 2, off2, 0, MATVEC_B, 1, -272)
        CHAINSTEP(sD, tb + 3, off3, 1, MATVEC_B, 1, -272)
    }
}

__global__ __launch_bounds__(64, 1)
void crf_chain(const float* __restrict__ logits, const int* __restrict__ lens,
               const float* __restrict__ Tg, int B, int nbh)
{
    if ((int)blockIdx.x < nbh) chainF(logits, lens, Tg, B, blockIdx.x);
    else                       chainB(logits, lens, Tg, B, blockIdx.x - nbh);
}

// Per sequence: P = sum_i Z_i * exp(logit_mid,i) * V_i ; norm = mf+mv+log P.
// Gold path score swept by all 64 lanes. One wave per sequence.
__global__ __launch_bounds__(64)
void crf_combine(const float* __restrict__ logits, const int* __restrict__ labels,
                 const int* __restrict__ lens, const float* __restrict__ T,
                 float* __restrict__ out, int B)
{
    const int b    = blockIdx.x;
    const int wtid = threadIdx.x;
    const int len  = lens[b];
    const int mid  = len >> 1;

    float prod = 0.0f;
    if (wtid < 17) {
        const float z  = g_Z[b * 17 + wtid];
        const float v  = g_V[b * 17 + wtid];
        const float lg = logits[(size_t)b * (S * NL) + mid * NL + wtid];
        prod = z * v * __expf(lg);
    }
    #pragma unroll
    for (int o = 32; o >= 1; o >>= 1) prod += __shfl_xor(prod, o);
    const float norm = g_mf[b] + g_mv[b] + __logf(prod);

    const int* labp = labels + b * S;
    float gsum = 0.0f;
    for (int c = 0; c < len; c += 64) {
        const int tok = c + wtid;
        if (tok < len) {
            const int lab = labp[tok];
            const int prv = (tok == 0) ? (L - 2) : labp[tok - 1];
            gsum += logits[(size_t)b * (S * NL) + tok * NL + lab] + T[lab * L + prv];
        }
    }
    #pragma unroll
    for (int o = 32; o >= 1; o >>= 1) gsum += __shfl_xor(gsum, o);
    const float gold = gsum + T[(L - 1) * L + labp[len - 1]];

    if (wtid == 0) out[b] = gold - norm;
}

extern "C" void kernel_launch(void* const* d_in, const int* in_sizes, int n_in,
                              void* d_out, int out_size, void* d_ws, size_t ws_size,
                              hipStream_t stream)
{
    (void)n_in; (void)out_size; (void)d_ws; (void)ws_size;
    const float* logits     = (const float*)d_in[0];
    const int*   labels     = (const int*)d_in[1];
    const int*   lens       = (const int*)d_in[2];
    const float* transition = (const float*)d_in[3];
    float*       out        = (float*)d_out;
    const int B   = in_sizes[2];
    const int NBH = (B + 63) / 64;

    crf_chain<<<dim3(2 * NBH), dim3(64), 0, stream>>>(logits, lens, transition, B, NBH);
    crf_combine<<<dim3(B), dim3(64), 0, stream>>>(logits, labels, lens, transition, out, B);
}